// Round 4
// baseline (215.173 us; speedup 1.0000x reference)
//
#include <hip/hip_runtime.h>

// MultiHeadAttentionBlock: N=4, S=1024, EMB=1024, H=16, D=64, f32 in/out.
// R4: GEMM gets counted-vmcnt deep pipeline (T3+T4): 4 LDS buffers,
// stage t+3 while computing t, s_waitcnt vmcnt(8) instead of barrier-drain.
// cvt + attention unchanged from R3.

typedef unsigned short u16;
typedef __attribute__((ext_vector_type(8))) short bf16x8;
typedef __attribute__((ext_vector_type(4))) float f32x4;

#define S_LEN 1024
#define EMB 1024
#define HEADS 16
#define HD 64

__device__ __forceinline__ u16 f2bf(float f) {
    unsigned int u = __float_as_uint(f);
    u = (u + 0x7fffu + ((u >> 16) & 1u)) >> 16;   // RNE
    return (u16)u;
}

typedef const __attribute__((address_space(1))) unsigned glob_u32;
typedef __attribute__((address_space(3))) unsigned lds_u32;
__device__ __forceinline__ void gld16(const u16* g, u16* l) {
    // async global->LDS, 16B per lane; LDS dest = wave-uniform base + lane*16
    __builtin_amdgcn_global_load_lds((glob_u32*)g, (lds_u32*)l, 16, 0, 0);
}

// ---------------------------------------------------------------------------
// f32 -> bf16 conversion for the 3 X inputs (1M float4 each) and 3 W (256K).
// ---------------------------------------------------------------------------
struct CvtArgs {
    const float* src[6];
    u16* dst[6];
};

__global__ __launch_bounds__(256) void cvt_f32_bf16(CvtArgs a)
{
    const long total = (3L << 20) + (3L << 18);   // float4 units
    for (long i = (long)blockIdx.x * 256 + threadIdx.x; i < total;
         i += (long)gridDim.x * 256) {
        int arr, off;
        if (i < (3L << 20)) { arr = (int)(i >> 20); off = (int)(i & ((1 << 20) - 1)); }
        else { long j = i - (3L << 20); arr = 3 + (int)(j >> 18); off = (int)(j & ((1 << 18) - 1)); }
        float4 v = reinterpret_cast<const float4*>(a.src[arr])[off];
        ushort4 o; o.x = f2bf(v.x); o.y = f2bf(v.y); o.z = f2bf(v.z); o.w = f2bf(v.w);
        reinterpret_cast<ushort4*>(a.dst[arr])[off] = o;
    }
}

// ---------------------------------------------------------------------------
// bf16 QKV GEMM, counted-vmcnt pipeline (R4).
// 128x128 tile, BK=32, 4 waves (2x2); 4 double-buffers of [128][32] bf16
// (64 KB LDS). Prologue stages tiles 0..2; per iter t:
//   s_waitcnt vmcnt(8)  -> oldest 4 loads (tile t) complete
//   s_barrier           -> tile t visible to all waves
//   stage(tile t+3)     -> 4 global_load_lds stay in flight across barriers
//   compute(tile t)     -> 8 ds_read_b128 + 16 MFMA
// Tail peeled with vmcnt(4)/vmcnt(0). Loads NEVER drained to 0 in main loop.
// ---------------------------------------------------------------------------
__global__ __launch_bounds__(256) void qkv_gemm_bf16(
    const u16* __restrict__ Xq, const u16* __restrict__ Xk, const u16* __restrict__ Xv,
    const u16* __restrict__ Wq, const u16* __restrict__ Wk, const u16* __restrict__ Wv,
    const float* __restrict__ Bq, const float* __restrict__ Bk, const float* __restrict__ Bv,
    u16* __restrict__ vt, u16* __restrict__ katt, u16* __restrict__ qatt)
{
    const int proj = blockIdx.z;
    const u16* X  = (proj == 0) ? Xq : (proj == 1) ? Xk : Xv;
    const u16* W  = (proj == 0) ? Wq : (proj == 1) ? Wk : Wv;
    const float* Bp = (proj == 0) ? Bq : (proj == 1) ? Bk : Bv;

    const int gm0 = blockIdx.x * 128;
    const int gn0 = blockIdx.y * 128;
    const int tid  = threadIdx.x;
    const int lane = tid & 63;
    const int wave = tid >> 6;
    const int wm = wave >> 1, wn = wave & 1;
    const int l15 = lane & 15, l4 = lane >> 4;

    __shared__ u16 As[4][128 * 32];   // 4 x 8KB, linear (global_load_lds dest)
    __shared__ u16 Bs[4][128 * 32];

    f32x4 acc[4][4];
    #pragma unroll
    for (int i = 0; i < 4; ++i)
        #pragma unroll
        for (int j = 0; j < 4; ++j) { f32x4 z = {0.f,0.f,0.f,0.f}; acc[i][j] = z; }

    // staging geometry (same verified mapping as R2/R3): chunk c = j*256+tid,
    // row = c>>2, col-chunk = c&3; LDS element offset for this lane:
    // buffer + j*2048 + wave*512 (+ lane*8 implicit in HW).
    const int r0 = tid >> 2,         cc0 = tid & 3;
    const int r1 = (tid + 256) >> 2, cc1 = (tid + 256) & 3;
    const u16* gA0 = X + (size_t)(gm0 + r0) * EMB + cc0 * 8;
    const u16* gA1 = X + (size_t)(gm0 + r1) * EMB + cc1 * 8;
    const u16* gB0 = W + (size_t)(gn0 + r0) * EMB + cc0 * 8;
    const u16* gB1 = W + (size_t)(gn0 + r1) * EMB + cc1 * 8;

    auto stage = [&](int buf, int ktile) {
        const int k0 = ktile * 32;
        u16* a = &As[buf][0] + wave * 512;
        u16* b = &Bs[buf][0] + wave * 512;
        gld16(gA0 + k0, a);
        gld16(gA1 + k0, a + 2048);
        gld16(gB0 + k0, b);
        gld16(gB1 + k0, b + 2048);
    };

    auto compute = [&](int kt) {
        const u16* A = &As[kt & 3][0];
        const u16* B = &Bs[kt & 3][0];
        bf16x8 af[4], bfr[4];
        #pragma unroll
        for (int m = 0; m < 4; ++m)
            af[m] = *reinterpret_cast<const bf16x8*>(&A[(wm * 64 + m * 16 + l15) * 32 + l4 * 8]);
        #pragma unroll
        for (int n = 0; n < 4; ++n)
            bfr[n] = *reinterpret_cast<const bf16x8*>(&B[(wn * 64 + n * 16 + l15) * 32 + l4 * 8]);
        #pragma unroll
        for (int m = 0; m < 4; ++m)
            #pragma unroll
            for (int n = 0; n < 4; ++n)
                acc[m][n] = __builtin_amdgcn_mfma_f32_16x16x32_bf16(af[m], bfr[n], acc[m][n], 0, 0, 0);
    };

    // prologue: 3 tiles in flight
    stage(0, 0);
    stage(1, 1);
    stage(2, 2);

    for (int kt = 0; kt < 30; ++kt) {
        asm volatile("s_waitcnt vmcnt(8)" ::: "memory");   // tile kt's 4 loads done
        __builtin_amdgcn_s_barrier();                       // visible to all waves
        if (kt <= 28) stage((kt + 3) & 3, kt + 3);          // keep 3 tiles in flight
        compute(kt);
    }
    asm volatile("s_waitcnt vmcnt(4)" ::: "memory");
    __builtin_amdgcn_s_barrier();
    compute(30);
    asm volatile("s_waitcnt vmcnt(0)" ::: "memory");
    __builtin_amdgcn_s_barrier();
    compute(31);

    // epilogue: + bias, bf16, scatter to attention layouts (verified R1-R3)
    #pragma unroll
    for (int n = 0; n < 4; ++n) {
        const int col = gn0 + wn * 64 + n * 16 + l15;
        const float bias = Bp[col];
        const int h = col >> 6, d = col & 63;
        #pragma unroll
        for (int m = 0; m < 4; ++m) {
            #pragma unroll
            for (int r = 0; r < 4; ++r) {
                const int rowg = gm0 + wm * 64 + m * 16 + l4 * 4 + r;
                const int nb = rowg >> 10, s = rowg & 1023;
                const u16 val = f2bf(acc[m][n][r] + bias);
                const int nh = nb * HEADS + h;
                if (proj == 0)       vt  [((size_t)nh * HD + d) * S_LEN + s] = val;
                else if (proj == 1)  katt[((size_t)nh * S_LEN + s) * HD + d] = val;
                else                 qatt[((size_t)nh * S_LEN + s) * HD + d] = val;
            }
        }
    }
}

// ---------------------------------------------------------------------------
// Fallback f32-input GEMM (used only if ws too small).
// ---------------------------------------------------------------------------
__global__ __launch_bounds__(256) void qkv_gemm_f32(
    const float* __restrict__ Xq, const float* __restrict__ Xk, const float* __restrict__ Xv,
    const float* __restrict__ Wq, const float* __restrict__ Wk, const float* __restrict__ Wv,
    const float* __restrict__ Bq, const float* __restrict__ Bk, const float* __restrict__ Bv,
    u16* __restrict__ vt, u16* __restrict__ katt, u16* __restrict__ qatt)
{
    const int proj = blockIdx.z;
    const float* X = (proj == 0) ? Xq : (proj == 1) ? Xk : Xv;
    const float* W = (proj == 0) ? Wq : (proj == 1) ? Wk : Wv;
    const float* Bp = (proj == 0) ? Bq : (proj == 1) ? Bk : Bv;

    const int gm0 = blockIdx.x * 128;
    const int gn0 = blockIdx.y * 128;
    const int tid  = threadIdx.x;
    const int lane = tid & 63;
    const int wave = tid >> 6;
    const int wm = wave >> 1, wn = wave & 1;
    const int l15 = lane & 15, l4 = lane >> 4;

    __shared__ u16 As[128 * 40];
    __shared__ u16 Bs[128 * 40];

    f32x4 acc[4][4];
    #pragma unroll
    for (int i = 0; i < 4; ++i)
        #pragma unroll
        for (int j = 0; j < 4; ++j) { f32x4 z = {0.f,0.f,0.f,0.f}; acc[i][j] = z; }

    const int srow = tid >> 3;
    const int skc  = (tid & 7) * 4;

    for (int kt = 0; kt < 32; ++kt) {
        const int k0 = kt * 32;
        #pragma unroll
        for (int p = 0; p < 4; ++p) {
            const int row = p * 32 + srow;
            float4 a = *reinterpret_cast<const float4*>(&X[(size_t)(gm0 + row) * EMB + k0 + skc]);
            float4 b = *reinterpret_cast<const float4*>(&W[(size_t)(gn0 + row) * EMB + k0 + skc]);
            ushort4 ua; ua.x = f2bf(a.x); ua.y = f2bf(a.y); ua.z = f2bf(a.z); ua.w = f2bf(a.w);
            ushort4 ub; ub.x = f2bf(b.x); ub.y = f2bf(b.y); ub.z = f2bf(b.z); ub.w = f2bf(b.w);
            *reinterpret_cast<ushort4*>(&As[row * 40 + skc]) = ua;
            *reinterpret_cast<ushort4*>(&Bs[row * 40 + skc]) = ub;
        }
        __syncthreads();

        bf16x8 af[4], bfr[4];
        #pragma unroll
        for (int m = 0; m < 4; ++m)
            af[m] = *reinterpret_cast<const bf16x8*>(&As[(wm * 64 + m * 16 + l15) * 40 + l4 * 8]);
        #pragma unroll
        for (int n = 0; n < 4; ++n)
            bfr[n] = *reinterpret_cast<const bf16x8*>(&Bs[(wn * 64 + n * 16 + l15) * 40 + l4 * 8]);

        #pragma unroll
        for (int m = 0; m < 4; ++m)
            #pragma unroll
            for (int n = 0; n < 4; ++n)
                acc[m][n] = __builtin_amdgcn_mfma_f32_16x16x32_bf16(af[m], bfr[n], acc[m][n], 0, 0, 0);
        __syncthreads();
    }

    #pragma unroll
    for (int n = 0; n < 4; ++n) {
        const int col = gn0 + wn * 64 + n * 16 + l15;
        const float bias = Bp[col];
        const int h = col >> 6, d = col & 63;
        #pragma unroll
        for (int m = 0; m < 4; ++m) {
            #pragma unroll
            for (int r = 0; r < 4; ++r) {
                const int rowg = gm0 + wm * 64 + m * 16 + l4 * 4 + r;
                const int nb = rowg >> 10, s = rowg & 1023;
                const u16 val = f2bf(acc[m][n][r] + bias);
                const int nh = nb * HEADS + h;
                if (proj == 0)       vt  [((size_t)nh * HD + d) * S_LEN + s] = val;
                else if (proj == 1)  katt[((size_t)nh * S_LEN + s) * HD + d] = val;
                else                 qatt[((size_t)nh * S_LEN + s) * HD + d] = val;
            }
        }
    }
}

// ---------------------------------------------------------------------------
// Flash attention (unchanged from R3 — verified).
// ---------------------------------------------------------------------------
__global__ __launch_bounds__(256) void attn_kernel(
    const u16* __restrict__ qatt, const u16* __restrict__ katt,
    const u16* __restrict__ vt, float* __restrict__ out)
{
    const int qb = blockIdx.x;
    const int nh = blockIdx.y;
    const int tid  = threadIdx.x;
    const int lane = tid & 63;
    const int wave = tid >> 6;
    const int l15 = lane & 15, l4 = lane >> 4;
    const int q0 = qb * 64;
    const int waveQ = wave * 16;

    __shared__ u16 Ks[2][64 * 64];
    __shared__ u16 Vs[2][64 * 64];
    __shared__ u16 Ps[4 * 16 * 72];

    const size_t qbase = (size_t)nh * S_LEN * HD + (size_t)(q0 + waveQ + l15) * HD;
    const bf16x8 qf0 = *reinterpret_cast<const bf16x8*>(&qatt[qbase + l4 * 8]);
    const bf16x8 qf1 = *reinterpret_cast<const bf16x8*>(&qatt[qbase + 32 + l4 * 8]);

    const int r8  = lane >> 3;
    const int ccg = (lane & 7) ^ r8;
    const int row0 = wave * 8 + r8;
    const int row1 = 32 + row0;
    const u16* gK = katt + (size_t)nh * S_LEN * HD;
    const u16* gV = vt   + (size_t)nh * HD * S_LEN;
    const u16* gK0 = gK + (size_t)row0 * HD + ccg * 8;
    const u16* gK1 = gK + (size_t)row1 * HD + ccg * 8;
    const u16* gV0 = gV + (size_t)row0 * S_LEN + ccg * 8;
    const u16* gV1 = gV + (size_t)row1 * S_LEN + ccg * 8;

    f32x4 accO[4];
    #pragma unroll
    for (int i = 0; i < 4; ++i) { f32x4 z = {0.f,0.f,0.f,0.f}; accO[i] = z; }
    float lsum[4] = {0.f, 0.f, 0.f, 0.f};
    const float scale = 0.03125f;

    {
        u16* kb = &Ks[0][0] + wave * 512;
        u16* vb = &Vs[0][0] + wave * 512;
        gld16(gK0, kb);          gld16(gK1, kb + 2048);
        gld16(gV0, vb);          gld16(gV1, vb + 2048);
    }
    __syncthreads();

    for (int kt = 0; kt < 16; ++kt) {
        const int cur = kt & 1;
        if (kt < 15) {
            const size_t kOff = (size_t)(kt + 1) * 64 * HD;
            const size_t vOff = (size_t)(kt + 1) * 64;
            u16* kb = &Ks[cur ^ 1][0] + wave * 512;
            u16* vb = &Vs[cur ^ 1][0] + wave * 512;
            gld16(gK0 + kOff, kb);       gld16(gK1 + kOff, kb + 2048);
            gld16(gV0 + vOff, vb);       gld16(gV1 + vOff, vb + 2048);
        }

        char* KsB = reinterpret_cast<char*>(&Ks[cur][0]);
        char* VsB = reinterpret_cast<char*>(&Vs[cur][0]);

        float pvals[4][4];
        #pragma unroll
        for (int kb = 0; kb < 4; ++kb) {
            const int krow = kb * 16 + l15;
            const int sw = krow & 7;
            bf16x8 kf0 = *reinterpret_cast<const bf16x8*>(KsB + krow * 128 + ((l4 ^ sw) << 4));
            bf16x8 kf1 = *reinterpret_cast<const bf16x8*>(KsB + krow * 128 + (((l4 + 4) ^ sw) << 4));
            f32x4 sacc = {0.f, 0.f, 0.f, 0.f};
            sacc = __builtin_amdgcn_mfma_f32_16x16x32_bf16(qf0, kf0, sacc, 0, 0, 0);
            sacc = __builtin_amdgcn_mfma_f32_16x16x32_bf16(qf1, kf1, sacc, 0, 0, 0);
            #pragma unroll
            for (int r = 0; r < 4; ++r) {
                const float pv = __expf(sacc[r] * scale);
                pvals[kb][r] = pv;
                lsum[r] += pv;
            }
        }

        u16* pw = &Ps[wave * 16 * 72];
        #pragma unroll
        for (int r = 0; r < 4; ++r) {
            const int prow = l4 * 4 + r;
            #pragma unroll
            for (int kb = 0; kb < 4; ++kb)
                pw[prow * 72 + kb * 16 + l15] = f2bf(pvals[kb][r]);
        }
        asm volatile("s_waitcnt lgkmcnt(0)" ::: "memory");
        __builtin_amdgcn_sched_barrier(0);

        const u16* pr = &Ps[wave * 16 * 72 + l15 * 72];
        const bf16x8 pf0 = *reinterpret_cast<const bf16x8*>(&pr[l4 * 8]);
        const bf16x8 pf1 = *reinterpret_cast<const bf16x8*>(&pr[32 + l4 * 8]);

        #pragma unroll
        for (int db = 0; db < 4; ++db) {
            const int vrow = db * 16 + l15;
            const int sw = vrow & 7;
            bf16x8 vf0 = *reinterpret_cast<const bf16x8*>(VsB + vrow * 128 + ((l4 ^ sw) << 4));
            bf16x8 vf1 = *reinterpret_cast<const bf16x8*>(VsB + vrow * 128 + (((l4 + 4) ^ sw) << 4));
            accO[db] = __builtin_amdgcn_mfma_f32_16x16x32_bf16(pf0, vf0, accO[db], 0, 0, 0);
            accO[db] = __builtin_amdgcn_mfma_f32_16x16x32_bf16(pf1, vf1, accO[db], 0, 0, 0);
        }
        __syncthreads();
    }

    #pragma unroll
    for (int r = 0; r < 4; ++r) {
        float s = lsum[r];
        #pragma unroll
        for (int msk = 1; msk < 16; msk <<= 1) s += __shfl_xor(s, msk);
        lsum[r] = 1.0f / s;
    }

    const int n = nh >> 4, h = nh & 15;
    #pragma unroll
    for (int db = 0; db < 4; ++db) {
        const int d = h * 64 + db * 16 + l15;
        #pragma unroll
        for (int r = 0; r < 4; ++r) {
            const int s = q0 + waveQ + l4 * 4 + r;
            out[(size_t)n * S_LEN * EMB + (size_t)s * EMB + d] = accO[db][r] * lsum[r];
        }
    }
}

extern "C" void kernel_launch(void* const* d_in, const int* in_sizes, int n_in,
                              void* d_out, int out_size, void* d_ws, size_t ws_size,
                              hipStream_t stream)
{
    const float* Xq = (const float*)d_in[0];
    const float* Xk = (const float*)d_in[1];
    const float* Xv = (const float*)d_in[2];
    const float* Wq = (const float*)d_in[3];
    const float* bq = (const float*)d_in[4];
    const float* Wk = (const float*)d_in[5];
    const float* bk = (const float*)d_in[6];
    const float* Wv = (const float*)d_in[7];
    const float* bv = (const float*)d_in[8];
    float* out = (float*)d_out;

    const size_t M4 = (size_t)4 * 1024 * 1024;   // u16 elements
    const size_t M1 = (size_t)1024 * 1024;

    u16* vt   = (u16*)d_ws;           // [64][64][1024]  V_att^T (q-proj)
    u16* katt = vt + M4;              // [64][1024][64]  K_att   (k-proj)
    u16* qatt = katt + M4;            // [64][1024][64]  Q_att   (v-proj)

    const size_t need = (3 * M4 + 3 * M4 + 3 * M1) * sizeof(u16);  // 54 MB

    if (ws_size >= need) {
        u16* Xqb = qatt + M4;
        u16* Xkb = Xqb + M4;
        u16* Xvb = Xkb + M4;
        u16* Wqb = Xvb + M4;
        u16* Wkb = Wqb + M1;
        u16* Wvb = Wkb + M1;

        CvtArgs ca;
        ca.src[0] = Xq; ca.src[1] = Xk; ca.src[2] = Xv;
        ca.src[3] = Wq; ca.src[4] = Wk; ca.src[5] = Wv;
        ca.dst[0] = Xqb; ca.dst[1] = Xkb; ca.dst[2] = Xvb;
        ca.dst[3] = Wqb; ca.dst[4] = Wkb; ca.dst[5] = Wvb;
        cvt_f32_bf16<<<2048, 256, 0, stream>>>(ca);

        qkv_gemm_bf16<<<dim3(32, 8, 3), 256, 0, stream>>>(
            Xqb, Xkb, Xvb, Wqb, Wkb, Wvb, bq, bk, bv, vt, katt, qatt);
    } else {
        qkv_gemm_f32<<<dim3(32, 8, 3), 256, 0, stream>>>(
            Xq, Xk, Xv, Wq, Wk, Wv, bq, bk, bv, vt, katt, qatt);
    }

    attn_kernel<<<dim3(16, 64), 256, 0, stream>>>(qatt, katt, vt, out);
}

// Round 5
// 211.365 us; speedup vs baseline: 1.0180x; 1.0180x over previous
//
#include <hip/hip_runtime.h>

// MultiHeadAttentionBlock: N=4, S=1024, EMB=1024, H=16, D=64, f32 in/out.
// R5: GEMM = counted-vmcnt depth-2 pipeline with 3 LDS buffers (48 KB,
// 3 blocks/CU) + T2 chunk-XOR swizzle killing the 8-way ds_read_b128 bank
// conflict + T5 setprio. Attn: + setprio around MFMA clusters.

typedef unsigned short u16;
typedef __attribute__((ext_vector_type(8))) short bf16x8;
typedef __attribute__((ext_vector_type(4))) float f32x4;

#define S_LEN 1024
#define EMB 1024
#define HEADS 16
#define HD 64

__device__ __forceinline__ u16 f2bf(float f) {
    unsigned int u = __float_as_uint(f);
    u = (u + 0x7fffu + ((u >> 16) & 1u)) >> 16;   // RNE
    return (u16)u;
}

typedef const __attribute__((address_space(1))) unsigned glob_u32;
typedef __attribute__((address_space(3))) unsigned lds_u32;
__device__ __forceinline__ void gld16(const u16* g, u16* l) {
    // async global->LDS, 16B per lane; LDS dest = wave-uniform base + lane*16
    __builtin_amdgcn_global_load_lds((glob_u32*)g, (lds_u32*)l, 16, 0, 0);
}

// ---------------------------------------------------------------------------
// f32 -> bf16 conversion for the 3 X inputs (1M float4 each) and 3 W (256K).
// ---------------------------------------------------------------------------
struct CvtArgs {
    const float* src[6];
    u16* dst[6];
};

__global__ __launch_bounds__(256) void cvt_f32_bf16(CvtArgs a)
{
    const long total = (3L << 20) + (3L << 18);   // float4 units
    for (long i = (long)blockIdx.x * 256 + threadIdx.x; i < total;
         i += (long)gridDim.x * 256) {
        int arr, off;
        if (i < (3L << 20)) { arr = (int)(i >> 20); off = (int)(i & ((1 << 20) - 1)); }
        else { long j = i - (3L << 20); arr = 3 + (int)(j >> 18); off = (int)(j & ((1 << 18) - 1)); }
        float4 v = reinterpret_cast<const float4*>(a.src[arr])[off];
        ushort4 o; o.x = f2bf(v.x); o.y = f2bf(v.y); o.z = f2bf(v.z); o.w = f2bf(v.w);
        reinterpret_cast<ushort4*>(a.dst[arr])[off] = o;
    }
}

// ---------------------------------------------------------------------------
// bf16 QKV GEMM (R5).
// 128x128 tile, BK=32, 4 waves (2x2). 3 LDS buffer pairs (48 KB).
// Pipeline: stage t+2 in flight; per iter: vmcnt(4) [tile t done, t+1 in
// flight] -> barrier -> stage(t+2) -> compute(t). Never drains to 0 in loop.
// T2 swizzle: LDS chunk (row,c) holds global chunk c ^ ((row>>1)&3); read
// side XORs the same -> granules 0,4,1,5,2,6,3,7 per 8 rows (2-way = free).
// ---------------------------------------------------------------------------
__global__ __launch_bounds__(256) void qkv_gemm_bf16(
    const u16* __restrict__ Xq, const u16* __restrict__ Xk, const u16* __restrict__ Xv,
    const u16* __restrict__ Wq, const u16* __restrict__ Wk, const u16* __restrict__ Wv,
    const float* __restrict__ Bq, const float* __restrict__ Bk, const float* __restrict__ Bv,
    u16* __restrict__ vt, u16* __restrict__ katt, u16* __restrict__ qatt)
{
    const int proj = blockIdx.z;
    const u16* X  = (proj == 0) ? Xq : (proj == 1) ? Xk : Xv;
    const u16* W  = (proj == 0) ? Wq : (proj == 1) ? Wk : Wv;
    const float* Bp = (proj == 0) ? Bq : (proj == 1) ? Bk : Bv;

    const int gm0 = blockIdx.x * 128;
    const int gn0 = blockIdx.y * 128;
    const int tid  = threadIdx.x;
    const int lane = tid & 63;
    const int wave = tid >> 6;
    const int wm = wave >> 1, wn = wave & 1;
    const int l15 = lane & 15, l4 = lane >> 4;

    __shared__ u16 As[3][128 * 32];   // 3 x 8KB, linear (global_load_lds dest)
    __shared__ u16 Bs[3][128 * 32];

    f32x4 acc[4][4];
    #pragma unroll
    for (int i = 0; i < 4; ++i)
        #pragma unroll
        for (int j = 0; j < 4; ++j) { f32x4 z = {0.f,0.f,0.f,0.f}; acc[i][j] = z; }

    // staging: HW writes LDS chunk j*256+tid linearly; row = chunk>>2,
    // c = chunk&3. Pre-swizzled SOURCE: global chunk = c ^ ((row>>1)&3)
    // = (tid&3) ^ ((tid>>3)&3)  (same for both j halves since 64>>1 = 32 ≡ 0 mod 4).
    const int rr  = tid >> 2;                       // row 0..63 within half
    const int ccg = (tid & 3) ^ ((tid >> 3) & 3);   // swizzled source chunk
    const u16* gA0 = X + (size_t)(gm0 + rr) * EMB + ccg * 8;
    const u16* gA1 = X + (size_t)(gm0 + 64 + rr) * EMB + ccg * 8;
    const u16* gB0 = W + (size_t)(gn0 + rr) * EMB + ccg * 8;
    const u16* gB1 = W + (size_t)(gn0 + 64 + rr) * EMB + ccg * 8;

    auto stage = [&](int buf, int ktile) {
        const int k0 = ktile * 32;
        u16* a = &As[buf][0] + wave * 512;
        u16* b = &Bs[buf][0] + wave * 512;
        gld16(gA0 + k0, a);
        gld16(gA1 + k0, a + 2048);
        gld16(gB0 + k0, b);
        gld16(gB1 + k0, b + 2048);
    };

    const int swz = (l15 >> 1) & 3;   // read-side chunk XOR
    auto compute = [&](int buf) {
        const u16* A = &As[buf][0];
        const u16* B = &Bs[buf][0];
        bf16x8 af[4], bfr[4];
        #pragma unroll
        for (int m = 0; m < 4; ++m)
            af[m] = *reinterpret_cast<const bf16x8*>(&A[(wm * 64 + m * 16 + l15) * 32 + (l4 ^ swz) * 8]);
        #pragma unroll
        for (int n = 0; n < 4; ++n)
            bfr[n] = *reinterpret_cast<const bf16x8*>(&B[(wn * 64 + n * 16 + l15) * 32 + (l4 ^ swz) * 8]);
        __builtin_amdgcn_s_setprio(1);
        #pragma unroll
        for (int m = 0; m < 4; ++m)
            #pragma unroll
            for (int n = 0; n < 4; ++n)
                acc[m][n] = __builtin_amdgcn_mfma_f32_16x16x32_bf16(af[m], bfr[n], acc[m][n], 0, 0, 0);
        __builtin_amdgcn_s_setprio(0);
    };

    // prologue: tiles 0,1 in flight
    stage(0, 0);
    stage(1, 1);

    #pragma unroll 1
    for (int base = 0; base < 30; base += 3) {
        asm volatile("s_waitcnt vmcnt(4)" ::: "memory");   // tile base done
        __builtin_amdgcn_s_barrier();
        stage(2, base + 2);
        compute(0);
        asm volatile("s_waitcnt vmcnt(4)" ::: "memory");   // tile base+1 done
        __builtin_amdgcn_s_barrier();
        stage(0, base + 3);
        compute(1);
        asm volatile("s_waitcnt vmcnt(4)" ::: "memory");   // tile base+2 done
        __builtin_amdgcn_s_barrier();
        stage(1, base + 4);
        compute(2);
    }
    // tiles 30 (buf0), 31 (buf1) remain; 8 loads outstanding
    asm volatile("s_waitcnt vmcnt(4)" ::: "memory");
    __builtin_amdgcn_s_barrier();
    compute(0);
    asm volatile("s_waitcnt vmcnt(0)" ::: "memory");
    __builtin_amdgcn_s_barrier();
    compute(1);

    // epilogue: + bias, bf16, scatter to attention layouts (verified R1-R4)
    #pragma unroll
    for (int n = 0; n < 4; ++n) {
        const int col = gn0 + wn * 64 + n * 16 + l15;
        const float bias = Bp[col];
        const int h = col >> 6, d = col & 63;
        #pragma unroll
        for (int m = 0; m < 4; ++m) {
            #pragma unroll
            for (int r = 0; r < 4; ++r) {
                const int rowg = gm0 + wm * 64 + m * 16 + l4 * 4 + r;
                const int nb = rowg >> 10, s = rowg & 1023;
                const u16 val = f2bf(acc[m][n][r] + bias);
                const int nh = nb * HEADS + h;
                if (proj == 0)       vt  [((size_t)nh * HD + d) * S_LEN + s] = val;
                else if (proj == 1)  katt[((size_t)nh * S_LEN + s) * HD + d] = val;
                else                 qatt[((size_t)nh * S_LEN + s) * HD + d] = val;
            }
        }
    }
}

// ---------------------------------------------------------------------------
// Fallback f32-input GEMM (used only if ws too small).
// ---------------------------------------------------------------------------
__global__ __launch_bounds__(256) void qkv_gemm_f32(
    const float* __restrict__ Xq, const float* __restrict__ Xk, const float* __restrict__ Xv,
    const float* __restrict__ Wq, const float* __restrict__ Wk, const float* __restrict__ Wv,
    const float* __restrict__ Bq, const float* __restrict__ Bk, const float* __restrict__ Bv,
    u16* __restrict__ vt, u16* __restrict__ katt, u16* __restrict__ qatt)
{
    const int proj = blockIdx.z;
    const float* X = (proj == 0) ? Xq : (proj == 1) ? Xk : Xv;
    const float* W = (proj == 0) ? Wq : (proj == 1) ? Wk : Wv;
    const float* Bp = (proj == 0) ? Bq : (proj == 1) ? Bk : Bv;

    const int gm0 = blockIdx.x * 128;
    const int gn0 = blockIdx.y * 128;
    const int tid  = threadIdx.x;
    const int lane = tid & 63;
    const int wave = tid >> 6;
    const int wm = wave >> 1, wn = wave & 1;
    const int l15 = lane & 15, l4 = lane >> 4;

    __shared__ u16 As[128 * 40];
    __shared__ u16 Bs[128 * 40];

    f32x4 acc[4][4];
    #pragma unroll
    for (int i = 0; i < 4; ++i)
        #pragma unroll
        for (int j = 0; j < 4; ++j) { f32x4 z = {0.f,0.f,0.f,0.f}; acc[i][j] = z; }

    const int srow = tid >> 3;
    const int skc  = (tid & 7) * 4;

    for (int kt = 0; kt < 32; ++kt) {
        const int k0 = kt * 32;
        #pragma unroll
        for (int p = 0; p < 4; ++p) {
            const int row = p * 32 + srow;
            float4 a = *reinterpret_cast<const float4*>(&X[(size_t)(gm0 + row) * EMB + k0 + skc]);
            float4 b = *reinterpret_cast<const float4*>(&W[(size_t)(gn0 + row) * EMB + k0 + skc]);
            ushort4 ua; ua.x = f2bf(a.x); ua.y = f2bf(a.y); ua.z = f2bf(a.z); ua.w = f2bf(a.w);
            ushort4 ub; ub.x = f2bf(b.x); ub.y = f2bf(b.y); ub.z = f2bf(b.z); ub.w = f2bf(b.w);
            *reinterpret_cast<ushort4*>(&As[row * 40 + skc]) = ua;
            *reinterpret_cast<ushort4*>(&Bs[row * 40 + skc]) = ub;
        }
        __syncthreads();

        bf16x8 af[4], bfr[4];
        #pragma unroll
        for (int m = 0; m < 4; ++m)
            af[m] = *reinterpret_cast<const bf16x8*>(&As[(wm * 64 + m * 16 + l15) * 40 + l4 * 8]);
        #pragma unroll
        for (int n = 0; n < 4; ++n)
            bfr[n] = *reinterpret_cast<const bf16x8*>(&Bs[(wn * 64 + n * 16 + l15) * 40 + l4 * 8]);

        #pragma unroll
        for (int m = 0; m < 4; ++m)
            #pragma unroll
            for (int n = 0; n < 4; ++n)
                acc[m][n] = __builtin_amdgcn_mfma_f32_16x16x32_bf16(af[m], bfr[n], acc[m][n], 0, 0, 0);
        __syncthreads();
    }

    #pragma unroll
    for (int n = 0; n < 4; ++n) {
        const int col = gn0 + wn * 64 + n * 16 + l15;
        const float bias = Bp[col];
        const int h = col >> 6, d = col & 63;
        #pragma unroll
        for (int m = 0; m < 4; ++m) {
            #pragma unroll
            for (int r = 0; r < 4; ++r) {
                const int rowg = gm0 + wm * 64 + m * 16 + l4 * 4 + r;
                const int nb = rowg >> 10, s = rowg & 1023;
                const u16 val = f2bf(acc[m][n][r] + bias);
                const int nh = nb * HEADS + h;
                if (proj == 0)       vt  [((size_t)nh * HD + d) * S_LEN + s] = val;
                else if (proj == 1)  katt[((size_t)nh * S_LEN + s) * HD + d] = val;
                else                 qatt[((size_t)nh * S_LEN + s) * HD + d] = val;
            }
        }
    }
}

// ---------------------------------------------------------------------------
// Flash attention (R3 structure + T5 setprio around MFMA clusters).
// ---------------------------------------------------------------------------
__global__ __launch_bounds__(256) void attn_kernel(
    const u16* __restrict__ qatt, const u16* __restrict__ katt,
    const u16* __restrict__ vt, float* __restrict__ out)
{
    const int qb = blockIdx.x;
    const int nh = blockIdx.y;
    const int tid  = threadIdx.x;
    const int lane = tid & 63;
    const int wave = tid >> 6;
    const int l15 = lane & 15, l4 = lane >> 4;
    const int q0 = qb * 64;
    const int waveQ = wave * 16;

    __shared__ u16 Ks[2][64 * 64];
    __shared__ u16 Vs[2][64 * 64];
    __shared__ u16 Ps[4 * 16 * 72];

    const size_t qbase = (size_t)nh * S_LEN * HD + (size_t)(q0 + waveQ + l15) * HD;
    const bf16x8 qf0 = *reinterpret_cast<const bf16x8*>(&qatt[qbase + l4 * 8]);
    const bf16x8 qf1 = *reinterpret_cast<const bf16x8*>(&qatt[qbase + 32 + l4 * 8]);

    const int r8  = lane >> 3;
    const int ccg = (lane & 7) ^ r8;
    const int row0 = wave * 8 + r8;
    const int row1 = 32 + row0;
    const u16* gK = katt + (size_t)nh * S_LEN * HD;
    const u16* gV = vt   + (size_t)nh * HD * S_LEN;
    const u16* gK0 = gK + (size_t)row0 * HD + ccg * 8;
    const u16* gK1 = gK + (size_t)row1 * HD + ccg * 8;
    const u16* gV0 = gV + (size_t)row0 * S_LEN + ccg * 8;
    const u16* gV1 = gV + (size_t)row1 * S_LEN + ccg * 8;

    f32x4 accO[4];
    #pragma unroll
    for (int i = 0; i < 4; ++i) { f32x4 z = {0.f,0.f,0.f,0.f}; accO[i] = z; }
    float lsum[4] = {0.f, 0.f, 0.f, 0.f};
    const float scale = 0.03125f;

    {
        u16* kb = &Ks[0][0] + wave * 512;
        u16* vb = &Vs[0][0] + wave * 512;
        gld16(gK0, kb);          gld16(gK1, kb + 2048);
        gld16(gV0, vb);          gld16(gV1, vb + 2048);
    }
    __syncthreads();

    for (int kt = 0; kt < 16; ++kt) {
        const int cur = kt & 1;
        if (kt < 15) {
            const size_t kOff = (size_t)(kt + 1) * 64 * HD;
            const size_t vOff = (size_t)(kt + 1) * 64;
            u16* kb = &Ks[cur ^ 1][0] + wave * 512;
            u16* vb = &Vs[cur ^ 1][0] + wave * 512;
            gld16(gK0 + kOff, kb);       gld16(gK1 + kOff, kb + 2048);
            gld16(gV0 + vOff, vb);       gld16(gV1 + vOff, vb + 2048);
        }

        char* KsB = reinterpret_cast<char*>(&Ks[cur][0]);
        char* VsB = reinterpret_cast<char*>(&Vs[cur][0]);

        float pvals[4][4];
        #pragma unroll
        for (int kb = 0; kb < 4; ++kb) {
            const int krow = kb * 16 + l15;
            const int sw = krow & 7;
            bf16x8 kf0 = *reinterpret_cast<const bf16x8*>(KsB + krow * 128 + ((l4 ^ sw) << 4));
            bf16x8 kf1 = *reinterpret_cast<const bf16x8*>(KsB + krow * 128 + (((l4 + 4) ^ sw) << 4));
            f32x4 sacc = {0.f, 0.f, 0.f, 0.f};
            __builtin_amdgcn_s_setprio(1);
            sacc = __builtin_amdgcn_mfma_f32_16x16x32_bf16(qf0, kf0, sacc, 0, 0, 0);
            sacc = __builtin_amdgcn_mfma_f32_16x16x32_bf16(qf1, kf1, sacc, 0, 0, 0);
            __builtin_amdgcn_s_setprio(0);
            #pragma unroll
            for (int r = 0; r < 4; ++r) {
                const float pv = __expf(sacc[r] * scale);
                pvals[kb][r] = pv;
                lsum[r] += pv;
            }
        }

        u16* pw = &Ps[wave * 16 * 72];
        #pragma unroll
        for (int r = 0; r < 4; ++r) {
            const int prow = l4 * 4 + r;
            #pragma unroll
            for (int kb = 0; kb < 4; ++kb)
                pw[prow * 72 + kb * 16 + l15] = f2bf(pvals[kb][r]);
        }
        asm volatile("s_waitcnt lgkmcnt(0)" ::: "memory");
        __builtin_amdgcn_sched_barrier(0);

        const u16* pr = &Ps[wave * 16 * 72 + l15 * 72];
        const bf16x8 pf0 = *reinterpret_cast<const bf16x8*>(&pr[l4 * 8]);
        const bf16x8 pf1 = *reinterpret_cast<const bf16x8*>(&pr[32 + l4 * 8]);

        __builtin_amdgcn_s_setprio(1);
        #pragma unroll
        for (int db = 0; db < 4; ++db) {
            const int vrow = db * 16 + l15;
            const int sw = vrow & 7;
            bf16x8 vf0 = *reinterpret_cast<const bf16x8*>(VsB + vrow * 128 + ((l4 ^ sw) << 4));
            bf16x8 vf1 = *reinterpret_cast<const bf16x8*>(VsB + vrow * 128 + (((l4 + 4) ^ sw) << 4));
            accO[db] = __builtin_amdgcn_mfma_f32_16x16x32_bf16(pf0, vf0, accO[db], 0, 0, 0);
            accO[db] = __builtin_amdgcn_mfma_f32_16x16x32_bf16(pf1, vf1, accO[db], 0, 0, 0);
        }
        __builtin_amdgcn_s_setprio(0);
        __syncthreads();
    }

    #pragma unroll
    for (int r = 0; r < 4; ++r) {
        float s = lsum[r];
        #pragma unroll
        for (int msk = 1; msk < 16; msk <<= 1) s += __shfl_xor(s, msk);
        lsum[r] = 1.0f / s;
    }

    const int n = nh >> 4, h = nh & 15;
    #pragma unroll
    for (int db = 0; db < 4; ++db) {
        const int d = h * 64 + db * 16 + l15;
        #pragma unroll
        for (int r = 0; r < 4; ++r) {
            const int s = q0 + waveQ + l4 * 4 + r;
            out[(size_t)n * S_LEN * EMB + (size_t)s * EMB + d] = accO[db][r] * lsum[r];
        }
    }
}

extern "C" void kernel_launch(void* const* d_in, const int* in_sizes, int n_in,
                              void* d_out, int out_size, void* d_ws, size_t ws_size,
                              hipStream_t stream)
{
    const float* Xq = (const float*)d_in[0];
    const float* Xk = (const float*)d_in[1];
    const float* Xv = (const float*)d_in[2];
    const float* Wq = (const float*)d_in[3];
    const float* bq = (const float*)d_in[4];
    const float* Wk = (const float*)d_in[5];
    const float* bk = (const float*)d_in[6];
    const float* Wv = (const float*)d_in[7];
    const float* bv = (const float*)d_in[8];
    float* out = (float*)d_out;

    const size_t M4 = (size_t)4 * 1024 * 1024;   // u16 elements
    const size_t M1 = (size_t)1024 * 1024;

    u16* vt   = (u16*)d_ws;           // [64][64][1024]  V_att^T (q-proj)
    u16* katt = vt + M4;              // [64][1024][64]  K_att   (k-proj)
    u16* qatt = katt + M4;            // [64][1024][64]  Q_att   (v-proj)

    const size_t need = (3 * M4 + 3 * M4 + 3 * M1) * sizeof(u16);  // 54 MB

    if (ws_size >= need) {
        u16* Xqb = qatt + M4;
        u16* Xkb = Xqb + M4;
        u16* Xvb = Xkb + M4;
        u16* Wqb = Xvb + M4;
        u16* Wkb = Wqb + M1;
        u16* Wvb = Wkb + M1;

        CvtArgs ca;
        ca.src[0] = Xq; ca.src[1] = Xk; ca.src[2] = Xv;
        ca.src[3] = Wq; ca.src[4] = Wk; ca.src[5] = Wv;
        ca.dst[0] = Xqb; ca.dst[1] = Xkb; ca.dst[2] = Xvb;
        ca.dst[3] = Wqb; ca.dst[4] = Wkb; ca.dst[5] = Wvb;
        cvt_f32_bf16<<<2048, 256, 0, stream>>>(ca);

        qkv_gemm_bf16<<<dim3(32, 8, 3), 256, 0, stream>>>(
            Xqb, Xkb, Xvb, Wqb, Wkb, Wvb, bq, bk, bv, vt, katt, qatt);
    } else {
        qkv_gemm_f32<<<dim3(32, 8, 3), 256, 0, stream>>>(
            Xq, Xk, Xv, Wq, Wk, Wv, bq, bk, bv, vt, katt, qatt);
    }

    attn_kernel<<<dim3(16, 64), 256, 0, stream>>>(qatt, katt, vt, out);
}

// Round 6
// 196.244 us; speedup vs baseline: 1.0965x; 1.0771x over previous
//
#include <hip/hip_runtime.h>

// MultiHeadAttentionBlock: N=4, S=1024, EMB=1024, H=16, D=64, f32 in/out.
// R6: GEMM goes to 8 waves/block (512 thr) on the same 128x128/BK=32 tile —
// doubles waves/CU to fight the measured latency-bound regime (occ 16%,
// all pipes idle). 3-buffer counted-vmcnt pipeline + T2 swizzle (conflicts=0,
// verified R5) retained. cvt + attention unchanged from R5.

typedef unsigned short u16;
typedef __attribute__((ext_vector_type(8))) short bf16x8;
typedef __attribute__((ext_vector_type(4))) float f32x4;

#define S_LEN 1024
#define EMB 1024
#define HEADS 16
#define HD 64

__device__ __forceinline__ u16 f2bf(float f) {
    unsigned int u = __float_as_uint(f);
    u = (u + 0x7fffu + ((u >> 16) & 1u)) >> 16;   // RNE
    return (u16)u;
}

typedef const __attribute__((address_space(1))) unsigned glob_u32;
typedef __attribute__((address_space(3))) unsigned lds_u32;
__device__ __forceinline__ void gld16(const u16* g, u16* l) {
    // async global->LDS, 16B per lane; LDS dest = wave-uniform base + lane*16
    __builtin_amdgcn_global_load_lds((glob_u32*)g, (lds_u32*)l, 16, 0, 0);
}

// ---------------------------------------------------------------------------
// f32 -> bf16 conversion for the 3 X inputs (1M float4 each) and 3 W (256K).
// ---------------------------------------------------------------------------
struct CvtArgs {
    const float* src[6];
    u16* dst[6];
};

__global__ __launch_bounds__(256) void cvt_f32_bf16(CvtArgs a)
{
    const long total = (3L << 20) + (3L << 18);   // float4 units
    for (long i = (long)blockIdx.x * 256 + threadIdx.x; i < total;
         i += (long)gridDim.x * 256) {
        int arr, off;
        if (i < (3L << 20)) { arr = (int)(i >> 20); off = (int)(i & ((1 << 20) - 1)); }
        else { long j = i - (3L << 20); arr = 3 + (int)(j >> 18); off = (int)(j & ((1 << 18) - 1)); }
        float4 v = reinterpret_cast<const float4*>(a.src[arr])[off];
        ushort4 o; o.x = f2bf(v.x); o.y = f2bf(v.y); o.z = f2bf(v.z); o.w = f2bf(v.w);
        reinterpret_cast<ushort4*>(a.dst[arr])[off] = o;
    }
}

// ---------------------------------------------------------------------------
// bf16 QKV GEMM (R6): 128x128 tile, BK=32, 8 waves (2x4), 512 threads.
// 3 LDS buffer pairs (48 KB -> 3 blocks/CU, 24 waves/CU theoretical).
// Per wave per K-step: 2 gld16 (stage), 6 ds_read_b128, 8 MFMA.
// Pipeline: stage t+2 in flight; per iter: vmcnt(2) [tile t done] ->
// barrier -> stage(t+2) -> compute(t). Never drains to 0 in the loop.
// T2 swizzle (verified conflict-free R5): LDS chunk j holds global chunk
// (j&3)^((j>>3)&3); read chunk = l4 ^ ((l15>>1)&3).
// ---------------------------------------------------------------------------
__global__ __launch_bounds__(512) void qkv_gemm_bf16(
    const u16* __restrict__ Xq, const u16* __restrict__ Xk, const u16* __restrict__ Xv,
    const u16* __restrict__ Wq, const u16* __restrict__ Wk, const u16* __restrict__ Wv,
    const float* __restrict__ Bq, const float* __restrict__ Bk, const float* __restrict__ Bv,
    u16* __restrict__ vt, u16* __restrict__ katt, u16* __restrict__ qatt)
{
    const int proj = blockIdx.z;
    const u16* X  = (proj == 0) ? Xq : (proj == 1) ? Xk : Xv;
    const u16* W  = (proj == 0) ? Wq : (proj == 1) ? Wk : Wv;
    const float* Bp = (proj == 0) ? Bq : (proj == 1) ? Bk : Bv;

    const int gm0 = blockIdx.x * 128;
    const int gn0 = blockIdx.y * 128;
    const int tid  = threadIdx.x;        // 0..511
    const int lane = tid & 63;
    const int wave = tid >> 6;           // 0..7
    const int wm = wave >> 2, wn = wave & 3;   // 2 x 4 wave grid
    const int l15 = lane & 15, l4 = lane >> 4;

    __shared__ u16 As[3][128 * 32];   // 3 x 8KB, linear (global_load_lds dest)
    __shared__ u16 Bs[3][128 * 32];

    f32x4 acc[4][2];
    #pragma unroll
    for (int i = 0; i < 4; ++i)
        #pragma unroll
        for (int j = 0; j < 2; ++j) { f32x4 z = {0.f,0.f,0.f,0.f}; acc[i][j] = z; }

    // staging: 512 chunks (128 rows x 4), one per thread. LDS linear;
    // pre-swizzled SOURCE chunk: (tid&3) ^ ((tid>>3)&3).
    const int rr  = tid >> 2;                       // row 0..127
    const int ccg = (tid & 3) ^ ((tid >> 3) & 3);   // swizzled source chunk
    const u16* gA = X + (size_t)(gm0 + rr) * EMB + ccg * 8;
    const u16* gB = W + (size_t)(gn0 + rr) * EMB + ccg * 8;

    auto stage = [&](int buf, int ktile) {
        const int k0 = ktile * 32;
        gld16(gA + k0, &As[buf][wave * 512]);
        gld16(gB + k0, &Bs[buf][wave * 512]);
    };

    const int swz = (l15 >> 1) & 3;   // read-side chunk XOR
    auto compute = [&](int buf) {
        const u16* A = &As[buf][0];
        const u16* B = &Bs[buf][0];
        bf16x8 af[4], bfr[2];
        #pragma unroll
        for (int m = 0; m < 4; ++m)
            af[m] = *reinterpret_cast<const bf16x8*>(&A[(wm * 64 + m * 16 + l15) * 32 + ((l4 ^ swz) * 8)]);
        #pragma unroll
        for (int n = 0; n < 2; ++n)
            bfr[n] = *reinterpret_cast<const bf16x8*>(&B[(wn * 32 + n * 16 + l15) * 32 + ((l4 ^ swz) * 8)]);
        __builtin_amdgcn_s_setprio(1);
        #pragma unroll
        for (int m = 0; m < 4; ++m)
            #pragma unroll
            for (int n = 0; n < 2; ++n)
                acc[m][n] = __builtin_amdgcn_mfma_f32_16x16x32_bf16(af[m], bfr[n], acc[m][n], 0, 0, 0);
        __builtin_amdgcn_s_setprio(0);
    };

    // prologue: tiles 0,1 in flight (2 loads each)
    stage(0, 0);
    stage(1, 1);

    #pragma unroll 1
    for (int base = 0; base < 30; base += 3) {
        asm volatile("s_waitcnt vmcnt(2)" ::: "memory");   // tile base done
        __builtin_amdgcn_s_barrier();
        stage(2, base + 2);
        compute(0);
        asm volatile("s_waitcnt vmcnt(2)" ::: "memory");   // tile base+1 done
        __builtin_amdgcn_s_barrier();
        stage(0, base + 3);
        compute(1);
        asm volatile("s_waitcnt vmcnt(2)" ::: "memory");   // tile base+2 done
        __builtin_amdgcn_s_barrier();
        stage(1, base + 4);
        compute(2);
    }
    // tiles 30 (buf0), 31 (buf1) remain; 4 loads outstanding
    asm volatile("s_waitcnt vmcnt(2)" ::: "memory");
    __builtin_amdgcn_s_barrier();
    compute(0);
    asm volatile("s_waitcnt vmcnt(0)" ::: "memory");
    __builtin_amdgcn_s_barrier();
    compute(1);

    // epilogue: + bias, bf16, scatter to attention layouts (verified R1-R5)
    #pragma unroll
    for (int n = 0; n < 2; ++n) {
        const int col = gn0 + wn * 32 + n * 16 + l15;
        const float bias = Bp[col];
        const int h = col >> 6, d = col & 63;
        #pragma unroll
        for (int m = 0; m < 4; ++m) {
            #pragma unroll
            for (int r = 0; r < 4; ++r) {
                const int rowg = gm0 + wm * 64 + m * 16 + l4 * 4 + r;
                const int nb = rowg >> 10, s = rowg & 1023;
                const u16 val = f2bf(acc[m][n][r] + bias);
                const int nh = nb * HEADS + h;
                if (proj == 0)       vt  [((size_t)nh * HD + d) * S_LEN + s] = val;
                else if (proj == 1)  katt[((size_t)nh * S_LEN + s) * HD + d] = val;
                else                 qatt[((size_t)nh * S_LEN + s) * HD + d] = val;
            }
        }
    }
}

// ---------------------------------------------------------------------------
// Fallback f32-input GEMM (used only if ws too small).
// ---------------------------------------------------------------------------
__global__ __launch_bounds__(256) void qkv_gemm_f32(
    const float* __restrict__ Xq, const float* __restrict__ Xk, const float* __restrict__ Xv,
    const float* __restrict__ Wq, const float* __restrict__ Wk, const float* __restrict__ Wv,
    const float* __restrict__ Bq, const float* __restrict__ Bk, const float* __restrict__ Bv,
    u16* __restrict__ vt, u16* __restrict__ katt, u16* __restrict__ qatt)
{
    const int proj = blockIdx.z;
    const float* X = (proj == 0) ? Xq : (proj == 1) ? Xk : Xv;
    const float* W = (proj == 0) ? Wq : (proj == 1) ? Wk : Wv;
    const float* Bp = (proj == 0) ? Bq : (proj == 1) ? Bk : Bv;

    const int gm0 = blockIdx.x * 128;
    const int gn0 = blockIdx.y * 128;
    const int tid  = threadIdx.x;
    const int lane = tid & 63;
    const int wave = tid >> 6;
    const int wm = wave >> 1, wn = wave & 1;
    const int l15 = lane & 15, l4 = lane >> 4;

    __shared__ u16 As[128 * 40];
    __shared__ u16 Bs[128 * 40];

    f32x4 acc[4][4];
    #pragma unroll
    for (int i = 0; i < 4; ++i)
        #pragma unroll
        for (int j = 0; j < 4; ++j) { f32x4 z = {0.f,0.f,0.f,0.f}; acc[i][j] = z; }

    const int srow = tid >> 3;
    const int skc  = (tid & 7) * 4;

    for (int kt = 0; kt < 32; ++kt) {
        const int k0 = kt * 32;
        #pragma unroll
        for (int p = 0; p < 4; ++p) {
            const int row = p * 32 + srow;
            float4 a = *reinterpret_cast<const float4*>(&X[(size_t)(gm0 + row) * EMB + k0 + skc]);
            float4 b = *reinterpret_cast<const float4*>(&W[(size_t)(gn0 + row) * EMB + k0 + skc]);
            ushort4 ua; ua.x = f2bf(a.x); ua.y = f2bf(a.y); ua.z = f2bf(a.z); ua.w = f2bf(a.w);
            ushort4 ub; ub.x = f2bf(b.x); ub.y = f2bf(b.y); ub.z = f2bf(b.z); ub.w = f2bf(b.w);
            *reinterpret_cast<ushort4*>(&As[row * 40 + skc]) = ua;
            *reinterpret_cast<ushort4*>(&Bs[row * 40 + skc]) = ub;
        }
        __syncthreads();

        bf16x8 af[4], bfr[4];
        #pragma unroll
        for (int m = 0; m < 4; ++m)
            af[m] = *reinterpret_cast<const bf16x8*>(&As[(wm * 64 + m * 16 + l15) * 40 + l4 * 8]);
        #pragma unroll
        for (int n = 0; n < 4; ++n)
            bfr[n] = *reinterpret_cast<const bf16x8*>(&Bs[(wn * 64 + n * 16 + l15) * 40 + l4 * 8]);

        #pragma unroll
        for (int m = 0; m < 4; ++m)
            #pragma unroll
            for (int n = 0; n < 4; ++n)
                acc[m][n] = __builtin_amdgcn_mfma_f32_16x16x32_bf16(af[m], bfr[n], acc[m][n], 0, 0, 0);
        __syncthreads();
    }

    #pragma unroll
    for (int n = 0; n < 4; ++n) {
        const int col = gn0 + wn * 64 + n * 16 + l15;
        const float bias = Bp[col];
        const int h = col >> 6, d = col & 63;
        #pragma unroll
        for (int m = 0; m < 4; ++m) {
            #pragma unroll
            for (int r = 0; r < 4; ++r) {
                const int rowg = gm0 + wm * 64 + m * 16 + l4 * 4 + r;
                const int nb = rowg >> 10, s = rowg & 1023;
                const u16 val = f2bf(acc[m][n][r] + bias);
                const int nh = nb * HEADS + h;
                if (proj == 0)       vt  [((size_t)nh * HD + d) * S_LEN + s] = val;
                else if (proj == 1)  katt[((size_t)nh * S_LEN + s) * HD + d] = val;
                else                 qatt[((size_t)nh * S_LEN + s) * HD + d] = val;
            }
        }
    }
}

// ---------------------------------------------------------------------------
// Flash attention (unchanged from R5 — verified).
// ---------------------------------------------------------------------------
__global__ __launch_bounds__(256) void attn_kernel(
    const u16* __restrict__ qatt, const u16* __restrict__ katt,
    const u16* __restrict__ vt, float* __restrict__ out)
{
    const int qb = blockIdx.x;
    const int nh = blockIdx.y;
    const int tid  = threadIdx.x;
    const int lane = tid & 63;
    const int wave = tid >> 6;
    const int l15 = lane & 15, l4 = lane >> 4;
    const int q0 = qb * 64;
    const int waveQ = wave * 16;

    __shared__ u16 Ks[2][64 * 64];
    __shared__ u16 Vs[2][64 * 64];
    __shared__ u16 Ps[4 * 16 * 72];

    const size_t qbase = (size_t)nh * S_LEN * HD + (size_t)(q0 + waveQ + l15) * HD;
    const bf16x8 qf0 = *reinterpret_cast<const bf16x8*>(&qatt[qbase + l4 * 8]);
    const bf16x8 qf1 = *reinterpret_cast<const bf16x8*>(&qatt[qbase + 32 + l4 * 8]);

    const int r8  = lane >> 3;
    const int ccg = (lane & 7) ^ r8;
    const int row0 = wave * 8 + r8;
    const int row1 = 32 + row0;
    const u16* gK = katt + (size_t)nh * S_LEN * HD;
    const u16* gV = vt   + (size_t)nh * HD * S_LEN;
    const u16* gK0 = gK + (size_t)row0 * HD + ccg * 8;
    const u16* gK1 = gK + (size_t)row1 * HD + ccg * 8;
    const u16* gV0 = gV + (size_t)row0 * S_LEN + ccg * 8;
    const u16* gV1 = gV + (size_t)row1 * S_LEN + ccg * 8;

    f32x4 accO[4];
    #pragma unroll
    for (int i = 0; i < 4; ++i) { f32x4 z = {0.f,0.f,0.f,0.f}; accO[i] = z; }
    float lsum[4] = {0.f, 0.f, 0.f, 0.f};
    const float scale = 0.03125f;

    {
        u16* kb = &Ks[0][0] + wave * 512;
        u16* vb = &Vs[0][0] + wave * 512;
        gld16(gK0, kb);          gld16(gK1, kb + 2048);
        gld16(gV0, vb);          gld16(gV1, vb + 2048);
    }
    __syncthreads();

    for (int kt = 0; kt < 16; ++kt) {
        const int cur = kt & 1;
        if (kt < 15) {
            const size_t kOff = (size_t)(kt + 1) * 64 * HD;
            const size_t vOff = (size_t)(kt + 1) * 64;
            u16* kb = &Ks[cur ^ 1][0] + wave * 512;
            u16* vb = &Vs[cur ^ 1][0] + wave * 512;
            gld16(gK0 + kOff, kb);       gld16(gK1 + kOff, kb + 2048);
            gld16(gV0 + vOff, vb);       gld16(gV1 + vOff, vb + 2048);
        }

        char* KsB = reinterpret_cast<char*>(&Ks[cur][0]);
        char* VsB = reinterpret_cast<char*>(&Vs[cur][0]);

        float pvals[4][4];
        #pragma unroll
        for (int kb = 0; kb < 4; ++kb) {
            const int krow = kb * 16 + l15;
            const int sw = krow & 7;
            bf16x8 kf0 = *reinterpret_cast<const bf16x8*>(KsB + krow * 128 + ((l4 ^ sw) << 4));
            bf16x8 kf1 = *reinterpret_cast<const bf16x8*>(KsB + krow * 128 + (((l4 + 4) ^ sw) << 4));
            f32x4 sacc = {0.f, 0.f, 0.f, 0.f};
            __builtin_amdgcn_s_setprio(1);
            sacc = __builtin_amdgcn_mfma_f32_16x16x32_bf16(qf0, kf0, sacc, 0, 0, 0);
            sacc = __builtin_amdgcn_mfma_f32_16x16x32_bf16(qf1, kf1, sacc, 0, 0, 0);
            __builtin_amdgcn_s_setprio(0);
            #pragma unroll
            for (int r = 0; r < 4; ++r) {
                const float pv = __expf(sacc[r] * scale);
                pvals[kb][r] = pv;
                lsum[r] += pv;
            }
        }

        u16* pw = &Ps[wave * 16 * 72];
        #pragma unroll
        for (int r = 0; r < 4; ++r) {
            const int prow = l4 * 4 + r;
            #pragma unroll
            for (int kb = 0; kb < 4; ++kb)
                pw[prow * 72 + kb * 16 + l15] = f2bf(pvals[kb][r]);
        }
        asm volatile("s_waitcnt lgkmcnt(0)" ::: "memory");
        __builtin_amdgcn_sched_barrier(0);

        const u16* pr = &Ps[wave * 16 * 72 + l15 * 72];
        const bf16x8 pf0 = *reinterpret_cast<const bf16x8*>(&pr[l4 * 8]);
        const bf16x8 pf1 = *reinterpret_cast<const bf16x8*>(&pr[32 + l4 * 8]);

        __builtin_amdgcn_s_setprio(1);
        #pragma unroll
        for (int db = 0; db < 4; ++db) {
            const int vrow = db * 16 + l15;
            const int sw = vrow & 7;
            bf16x8 vf0 = *reinterpret_cast<const bf16x8*>(VsB + vrow * 128 + ((l4 ^ sw) << 4));
            bf16x8 vf1 = *reinterpret_cast<const bf16x8*>(VsB + vrow * 128 + (((l4 + 4) ^ sw) << 4));
            accO[db] = __builtin_amdgcn_mfma_f32_16x16x32_bf16(pf0, vf0, accO[db], 0, 0, 0);
            accO[db] = __builtin_amdgcn_mfma_f32_16x16x32_bf16(pf1, vf1, accO[db], 0, 0, 0);
        }
        __builtin_amdgcn_s_setprio(0);
        __syncthreads();
    }

    #pragma unroll
    for (int r = 0; r < 4; ++r) {
        float s = lsum[r];
        #pragma unroll
        for (int msk = 1; msk < 16; msk <<= 1) s += __shfl_xor(s, msk);
        lsum[r] = 1.0f / s;
    }

    const int n = nh >> 4, h = nh & 15;
    #pragma unroll
    for (int db = 0; db < 4; ++db) {
        const int d = h * 64 + db * 16 + l15;
        #pragma unroll
        for (int r = 0; r < 4; ++r) {
            const int s = q0 + waveQ + l4 * 4 + r;
            out[(size_t)n * S_LEN * EMB + (size_t)s * EMB + d] = accO[db][r] * lsum[r];
        }
    }
}

extern "C" void kernel_launch(void* const* d_in, const int* in_sizes, int n_in,
                              void* d_out, int out_size, void* d_ws, size_t ws_size,
                              hipStream_t stream)
{
    const float* Xq = (const float*)d_in[0];
    const float* Xk = (const float*)d_in[1];
    const float* Xv = (const float*)d_in[2];
    const float* Wq = (const float*)d_in[3];
    const float* bq = (const float*)d_in[4];
    const float* Wk = (const float*)d_in[5];
    const float* bk = (const float*)d_in[6];
    const float* Wv = (const float*)d_in[7];
    const float* bv = (const float*)d_in[8];
    float* out = (float*)d_out;

    const size_t M4 = (size_t)4 * 1024 * 1024;   // u16 elements
    const size_t M1 = (size_t)1024 * 1024;

    u16* vt   = (u16*)d_ws;           // [64][64][1024]  V_att^T (q-proj)
    u16* katt = vt + M4;              // [64][1024][64]  K_att   (k-proj)
    u16* qatt = katt + M4;            // [64][1024][64]  Q_att   (v-proj)

    const size_t need = (3 * M4 + 3 * M4 + 3 * M1) * sizeof(u16);  // 54 MB

    if (ws_size >= need) {
        u16* Xqb = qatt + M4;
        u16* Xkb = Xqb + M4;
        u16* Xvb = Xkb + M4;
        u16* Wqb = Xvb + M4;
        u16* Wkb = Wqb + M1;
        u16* Wvb = Wkb + M1;

        CvtArgs ca;
        ca.src[0] = Xq; ca.src[1] = Xk; ca.src[2] = Xv;
        ca.src[3] = Wq; ca.src[4] = Wk; ca.src[5] = Wv;
        ca.dst[0] = Xqb; ca.dst[1] = Xkb; ca.dst[2] = Xvb;
        ca.dst[3] = Wqb; ca.dst[4] = Wkb; ca.dst[5] = Wvb;
        cvt_f32_bf16<<<2048, 256, 0, stream>>>(ca);

        qkv_gemm_bf16<<<dim3(32, 8, 3), 512, 0, stream>>>(
            Xqb, Xkb, Xvb, Wqb, Wkb, Wvb, bq, bk, bv, vt, katt, qatt);
    } else {
        qkv_gemm_f32<<<dim3(32, 8, 3), 256, 0, stream>>>(
            Xq, Xk, Xv, Wq, Wk, Wv, bq, bk, bv, vt, katt, qatt);
    }

    attn_kernel<<<dim3(16, 64), 256, 0, stream>>>(qatt, katt, vt, out);
}

// Round 8
// 189.608 us; speedup vs baseline: 1.1348x; 1.0350x over previous
//
#include <hip/hip_runtime.h>

// MultiHeadAttentionBlock: N=4, S=1024, EMB=1024, H=16, D=64, f32 in/out.
// R8 = R7 resubmitted (R7 bench was an infra failure, no data).
// Attention: T12 — swapped QK^T (mfma(K,Q)) so P is lane-local,
// cvt_pk_bf16 + shfl builds PV A-frags in-register. P LDS roundtrip (and its
// 8-way bank conflict, 524K/dispatch) deleted. GEMM/cvt unchanged from R6.

typedef unsigned short u16;
typedef __attribute__((ext_vector_type(8))) short bf16x8;
typedef __attribute__((ext_vector_type(4))) float f32x4;

#define S_LEN 1024
#define EMB 1024
#define HEADS 16
#define HD 64

__device__ __forceinline__ u16 f2bf(float f) {
    unsigned int u = __float_as_uint(f);
    u = (u + 0x7fffu + ((u >> 16) & 1u)) >> 16;   // RNE
    return (u16)u;
}

typedef const __attribute__((address_space(1))) unsigned glob_u32;
typedef __attribute__((address_space(3))) unsigned lds_u32;
__device__ __forceinline__ void gld16(const u16* g, u16* l) {
    // async global->LDS, 16B per lane; LDS dest = wave-uniform base + lane*16
    __builtin_amdgcn_global_load_lds((glob_u32*)g, (lds_u32*)l, 16, 0, 0);
}

// ---------------------------------------------------------------------------
// f32 -> bf16 conversion for the 3 X inputs (1M float4 each) and 3 W (256K).
// ---------------------------------------------------------------------------
struct CvtArgs {
    const float* src[6];
    u16* dst[6];
};

__global__ __launch_bounds__(256) void cvt_f32_bf16(CvtArgs a)
{
    const long total = (3L << 20) + (3L << 18);   // float4 units
    for (long i = (long)blockIdx.x * 256 + threadIdx.x; i < total;
         i += (long)gridDim.x * 256) {
        int arr, off;
        if (i < (3L << 20)) { arr = (int)(i >> 20); off = (int)(i & ((1 << 20) - 1)); }
        else { long j = i - (3L << 20); arr = 3 + (int)(j >> 18); off = (int)(j & ((1 << 18) - 1)); }
        float4 v = reinterpret_cast<const float4*>(a.src[arr])[off];
        ushort4 o; o.x = f2bf(v.x); o.y = f2bf(v.y); o.z = f2bf(v.z); o.w = f2bf(v.w);
        reinterpret_cast<ushort4*>(a.dst[arr])[off] = o;
    }
}

// ---------------------------------------------------------------------------
// bf16 QKV GEMM (R6, unchanged): 128x128 tile, BK=32, 8 waves (2x4), 512 thr.
// 3 LDS buffer pairs, counted-vmcnt pipeline, T2 swizzle (conflicts=0).
// ---------------------------------------------------------------------------
__global__ __launch_bounds__(512) void qkv_gemm_bf16(
    const u16* __restrict__ Xq, const u16* __restrict__ Xk, const u16* __restrict__ Xv,
    const u16* __restrict__ Wq, const u16* __restrict__ Wk, const u16* __restrict__ Wv,
    const float* __restrict__ Bq, const float* __restrict__ Bk, const float* __restrict__ Bv,
    u16* __restrict__ vt, u16* __restrict__ katt, u16* __restrict__ qatt)
{
    const int proj = blockIdx.z;
    const u16* X  = (proj == 0) ? Xq : (proj == 1) ? Xk : Xv;
    const u16* W  = (proj == 0) ? Wq : (proj == 1) ? Wk : Wv;
    const float* Bp = (proj == 0) ? Bq : (proj == 1) ? Bk : Bv;

    const int gm0 = blockIdx.x * 128;
    const int gn0 = blockIdx.y * 128;
    const int tid  = threadIdx.x;        // 0..511
    const int lane = tid & 63;
    const int wave = tid >> 6;           // 0..7
    const int wm = wave >> 2, wn = wave & 3;   // 2 x 4 wave grid
    const int l15 = lane & 15, l4 = lane >> 4;

    __shared__ u16 As[3][128 * 32];   // 3 x 8KB, linear (global_load_lds dest)
    __shared__ u16 Bs[3][128 * 32];

    f32x4 acc[4][2];
    #pragma unroll
    for (int i = 0; i < 4; ++i)
        #pragma unroll
        for (int j = 0; j < 2; ++j) { f32x4 z = {0.f,0.f,0.f,0.f}; acc[i][j] = z; }

    const int rr  = tid >> 2;                       // row 0..127
    const int ccg = (tid & 3) ^ ((tid >> 3) & 3);   // swizzled source chunk
    const u16* gA = X + (size_t)(gm0 + rr) * EMB + ccg * 8;
    const u16* gB = W + (size_t)(gn0 + rr) * EMB + ccg * 8;

    auto stage = [&](int buf, int ktile) {
        const int k0 = ktile * 32;
        gld16(gA + k0, &As[buf][wave * 512]);
        gld16(gB + k0, &Bs[buf][wave * 512]);
    };

    const int swz = (l15 >> 1) & 3;   // read-side chunk XOR
    auto compute = [&](int buf) {
        const u16* A = &As[buf][0];
        const u16* B = &Bs[buf][0];
        bf16x8 af[4], bfr[2];
        #pragma unroll
        for (int m = 0; m < 4; ++m)
            af[m] = *reinterpret_cast<const bf16x8*>(&A[(wm * 64 + m * 16 + l15) * 32 + ((l4 ^ swz) * 8)]);
        #pragma unroll
        for (int n = 0; n < 2; ++n)
            bfr[n] = *reinterpret_cast<const bf16x8*>(&B[(wn * 32 + n * 16 + l15) * 32 + ((l4 ^ swz) * 8)]);
        __builtin_amdgcn_s_setprio(1);
        #pragma unroll
        for (int m = 0; m < 4; ++m)
            #pragma unroll
            for (int n = 0; n < 2; ++n)
                acc[m][n] = __builtin_amdgcn_mfma_f32_16x16x32_bf16(af[m], bfr[n], acc[m][n], 0, 0, 0);
        __builtin_amdgcn_s_setprio(0);
    };

    stage(0, 0);
    stage(1, 1);

    #pragma unroll 1
    for (int base = 0; base < 30; base += 3) {
        asm volatile("s_waitcnt vmcnt(2)" ::: "memory");
        __builtin_amdgcn_s_barrier();
        stage(2, base + 2);
        compute(0);
        asm volatile("s_waitcnt vmcnt(2)" ::: "memory");
        __builtin_amdgcn_s_barrier();
        stage(0, base + 3);
        compute(1);
        asm volatile("s_waitcnt vmcnt(2)" ::: "memory");
        __builtin_amdgcn_s_barrier();
        stage(1, base + 4);
        compute(2);
    }
    asm volatile("s_waitcnt vmcnt(2)" ::: "memory");
    __builtin_amdgcn_s_barrier();
    compute(0);
    asm volatile("s_waitcnt vmcnt(0)" ::: "memory");
    __builtin_amdgcn_s_barrier();
    compute(1);

    #pragma unroll
    for (int n = 0; n < 2; ++n) {
        const int col = gn0 + wn * 32 + n * 16 + l15;
        const float bias = Bp[col];
        const int h = col >> 6, d = col & 63;
        #pragma unroll
        for (int m = 0; m < 4; ++m) {
            #pragma unroll
            for (int r = 0; r < 4; ++r) {
                const int rowg = gm0 + wm * 64 + m * 16 + l4 * 4 + r;
                const int nb = rowg >> 10, s = rowg & 1023;
                const u16 val = f2bf(acc[m][n][r] + bias);
                const int nh = nb * HEADS + h;
                if (proj == 0)       vt  [((size_t)nh * HD + d) * S_LEN + s] = val;
                else if (proj == 1)  katt[((size_t)nh * S_LEN + s) * HD + d] = val;
                else                 qatt[((size_t)nh * S_LEN + s) * HD + d] = val;
            }
        }
    }
}

// ---------------------------------------------------------------------------
// Fallback f32-input GEMM (used only if ws too small).
// ---------------------------------------------------------------------------
__global__ __launch_bounds__(256) void qkv_gemm_f32(
    const float* __restrict__ Xq, const float* __restrict__ Xk, const float* __restrict__ Xv,
    const float* __restrict__ Wq, const float* __restrict__ Wk, const float* __restrict__ Wv,
    const float* __restrict__ Bq, const float* __restrict__ Bk, const float* __restrict__ Bv,
    u16* __restrict__ vt, u16* __restrict__ katt, u16* __restrict__ qatt)
{
    const int proj = blockIdx.z;
    const float* X = (proj == 0) ? Xq : (proj == 1) ? Xk : Xv;
    const float* W = (proj == 0) ? Wq : (proj == 1) ? Wk : Wv;
    const float* Bp = (proj == 0) ? Bq : (proj == 1) ? Bk : Bv;

    const int gm0 = blockIdx.x * 128;
    const int gn0 = blockIdx.y * 128;
    const int tid  = threadIdx.x;
    const int lane = tid & 63;
    const int wave = tid >> 6;
    const int wm = wave >> 1, wn = wave & 1;
    const int l15 = lane & 15, l4 = lane >> 4;

    __shared__ u16 As[128 * 40];
    __shared__ u16 Bs[128 * 40];

    f32x4 acc[4][4];
    #pragma unroll
    for (int i = 0; i < 4; ++i)
        #pragma unroll
        for (int j = 0; j < 4; ++j) { f32x4 z = {0.f,0.f,0.f,0.f}; acc[i][j] = z; }

    const int srow = tid >> 3;
    const int skc  = (tid & 7) * 4;

    for (int kt = 0; kt < 32; ++kt) {
        const int k0 = kt * 32;
        #pragma unroll
        for (int p = 0; p < 4; ++p) {
            const int row = p * 32 + srow;
            float4 a = *reinterpret_cast<const float4*>(&X[(size_t)(gm0 + row) * EMB + k0 + skc]);
            float4 b = *reinterpret_cast<const float4*>(&W[(size_t)(gn0 + row) * EMB + k0 + skc]);
            ushort4 ua; ua.x = f2bf(a.x); ua.y = f2bf(a.y); ua.z = f2bf(a.z); ua.w = f2bf(a.w);
            ushort4 ub; ub.x = f2bf(b.x); ub.y = f2bf(b.y); ub.z = f2bf(b.z); ub.w = f2bf(b.w);
            *reinterpret_cast<ushort4*>(&As[row * 40 + skc]) = ua;
            *reinterpret_cast<ushort4*>(&Bs[row * 40 + skc]) = ub;
        }
        __syncthreads();

        bf16x8 af[4], bfr[4];
        #pragma unroll
        for (int m = 0; m < 4; ++m)
            af[m] = *reinterpret_cast<const bf16x8*>(&As[(wm * 64 + m * 16 + l15) * 40 + l4 * 8]);
        #pragma unroll
        for (int n = 0; n < 4; ++n)
            bfr[n] = *reinterpret_cast<const bf16x8*>(&Bs[(wn * 64 + n * 16 + l15) * 40 + l4 * 8]);

        #pragma unroll
        for (int m = 0; m < 4; ++m)
            #pragma unroll
            for (int n = 0; n < 4; ++n)
                acc[m][n] = __builtin_amdgcn_mfma_f32_16x16x32_bf16(af[m], bfr[n], acc[m][n], 0, 0, 0);
        __syncthreads();
    }

    #pragma unroll
    for (int n = 0; n < 4; ++n) {
        const int col = gn0 + wn * 64 + n * 16 + l15;
        const float bias = Bp[col];
        const int h = col >> 6, d = col & 63;
        #pragma unroll
        for (int m = 0; m < 4; ++m) {
            #pragma unroll
            for (int r = 0; r < 4; ++r) {
                const int rowg = gm0 + wm * 64 + m * 16 + l4 * 4 + r;
                const int nb = rowg >> 10, s = rowg & 1023;
                const u16 val = f2bf(acc[m][n][r] + bias);
                const int nh = nb * HEADS + h;
                if (proj == 0)       vt  [((size_t)nh * HD + d) * S_LEN + s] = val;
                else if (proj == 1)  katt[((size_t)nh * S_LEN + s) * HD + d] = val;
                else                 qatt[((size_t)nh * S_LEN + s) * HD + d] = val;
            }
        }
    }
}

// ---------------------------------------------------------------------------
// Flash attention R7: swapped QK^T (T12) -> P lane-local; cvt_pk + shfl
// rebuild PV A-frags in-register. No P LDS. No-max softmax (verified R3+).
// Layout algebra (HW-verified C/D map D[row=l4*4+r][col=l15]):
//  - QK: mfma(A=kf,B=qf) -> P[key=kb*16+l4*4+r][q=l15] in sacc[r]
//  - pack: pk[kb][j] = cvt_pk(pv[2j], pv[2j+1]) = keys kb*16+l4*4+2j..+1
//  - PV A-frag (lane l15,l4 wants q=l15, keys l4*8..+7):
//      word w<2 : from lane srcA = l15+32*(l4&1),  pk[kb][w]
//      word w>=2: from lane srcB = srcA+16,        pk[kb][w-2]
//      kb = l4>>1 for pf0 (keys 0..31), kb = 2+(l4>>1) for pf1 (keys 32..63)
// ---------------------------------------------------------------------------
__global__ __launch_bounds__(256) void attn_kernel(
    const u16* __restrict__ qatt, const u16* __restrict__ katt,
    const u16* __restrict__ vt, float* __restrict__ out)
{
    const int qb = blockIdx.x;
    const int nh = blockIdx.y;
    const int tid  = threadIdx.x;
    const int lane = tid & 63;
    const int wave = tid >> 6;
    const int l15 = lane & 15, l4 = lane >> 4;
    const int q0 = qb * 64;
    const int waveQ = wave * 16;

    __shared__ u16 Ks[2][64 * 64];
    __shared__ u16 Vs[2][64 * 64];

    const size_t qbase = (size_t)nh * S_LEN * HD + (size_t)(q0 + waveQ + l15) * HD;
    const bf16x8 qf0 = *reinterpret_cast<const bf16x8*>(&qatt[qbase + l4 * 8]);
    const bf16x8 qf1 = *reinterpret_cast<const bf16x8*>(&qatt[qbase + 32 + l4 * 8]);

    const int r8  = lane >> 3;
    const int ccg = (lane & 7) ^ r8;
    const int row0 = wave * 8 + r8;
    const int row1 = 32 + row0;
    const u16* gK = katt + (size_t)nh * S_LEN * HD;
    const u16* gV = vt   + (size_t)nh * HD * S_LEN;
    const u16* gK0 = gK + (size_t)row0 * HD + ccg * 8;
    const u16* gK1 = gK + (size_t)row1 * HD + ccg * 8;
    const u16* gV0 = gV + (size_t)row0 * S_LEN + ccg * 8;
    const u16* gV1 = gV + (size_t)row1 * S_LEN + ccg * 8;

    f32x4 accO[4];
    #pragma unroll
    for (int i = 0; i < 4; ++i) { f32x4 z = {0.f,0.f,0.f,0.f}; accO[i] = z; }
    float lsum = 0.f;                 // partial denom for q = l15 (lane-local)
    const float scale = 0.03125f;     // 1/sqrt(1024)

    {
        u16* kb = &Ks[0][0] + wave * 512;
        u16* vb = &Vs[0][0] + wave * 512;
        gld16(gK0, kb);          gld16(gK1, kb + 2048);
        gld16(gV0, vb);          gld16(gV1, vb + 2048);
    }
    __syncthreads();

    const int srcA = l15 + ((l4 & 1) << 5);
    const int srcB = srcA + 16;
    const bool lo = (l4 < 2);

    for (int kt = 0; kt < 16; ++kt) {
        const int cur = kt & 1;
        if (kt < 15) {
            const size_t kOff = (size_t)(kt + 1) * 64 * HD;
            const size_t vOff = (size_t)(kt + 1) * 64;
            u16* kb = &Ks[cur ^ 1][0] + wave * 512;
            u16* vb = &Vs[cur ^ 1][0] + wave * 512;
            gld16(gK0 + kOff, kb);       gld16(gK1 + kOff, kb + 2048);
            gld16(gV0 + vOff, vb);       gld16(gV1 + vOff, vb + 2048);
        }

        char* KsB = reinterpret_cast<char*>(&Ks[cur][0]);
        char* VsB = reinterpret_cast<char*>(&Vs[cur][0]);

        // P = exp(K Q^T / 32): lane holds P[key=kb*16+l4*4+r][q=l15]
        float pv[4][4];
        #pragma unroll
        for (int kb = 0; kb < 4; ++kb) {
            const int krow = kb * 16 + l15;
            const int sw = krow & 7;
            bf16x8 kf0 = *reinterpret_cast<const bf16x8*>(KsB + krow * 128 + ((l4 ^ sw) << 4));
            bf16x8 kf1 = *reinterpret_cast<const bf16x8*>(KsB + krow * 128 + (((l4 + 4) ^ sw) << 4));
            f32x4 sacc = {0.f, 0.f, 0.f, 0.f};
            __builtin_amdgcn_s_setprio(1);
            sacc = __builtin_amdgcn_mfma_f32_16x16x32_bf16(kf0, qf0, sacc, 0, 0, 0);  // swapped
            sacc = __builtin_amdgcn_mfma_f32_16x16x32_bf16(kf1, qf1, sacc, 0, 0, 0);
            __builtin_amdgcn_s_setprio(0);
            #pragma unroll
            for (int r = 0; r < 4; ++r) {
                const float p = __expf(sacc[r] * scale);
                pv[kb][r] = p;
                lsum += p;
            }
        }

        // pack P to bf16 pairs (keys +0,+1 / +2,+3 per kb)
        unsigned pk0l, pk0h, pk1l, pk1h, pk2l, pk2h, pk3l, pk3h;
        asm("v_cvt_pk_bf16_f32 %0, %1, %2" : "=v"(pk0l) : "v"(pv[0][0]), "v"(pv[0][1]));
        asm("v_cvt_pk_bf16_f32 %0, %1, %2" : "=v"(pk0h) : "v"(pv[0][2]), "v"(pv[0][3]));
        asm("v_cvt_pk_bf16_f32 %0, %1, %2" : "=v"(pk1l) : "v"(pv[1][0]), "v"(pv[1][1]));
        asm("v_cvt_pk_bf16_f32 %0, %1, %2" : "=v"(pk1h) : "v"(pv[1][2]), "v"(pv[1][3]));
        asm("v_cvt_pk_bf16_f32 %0, %1, %2" : "=v"(pk2l) : "v"(pv[2][0]), "v"(pv[2][1]));
        asm("v_cvt_pk_bf16_f32 %0, %1, %2" : "=v"(pk2h) : "v"(pv[2][2]), "v"(pv[2][3]));
        asm("v_cvt_pk_bf16_f32 %0, %1, %2" : "=v"(pk3l) : "v"(pv[3][0]), "v"(pv[3][1]));
        asm("v_cvt_pk_bf16_f32 %0, %1, %2" : "=v"(pk3h) : "v"(pv[3][2]), "v"(pv[3][3]));

        // shuffle into PV A-frags (q=l15, keys l4*8..+7 | 32+l4*8..+7)
        int a, b;
        int w0, w1, w2, w3, x0, x1, x2, x3;
        a = __shfl((int)pk0l, srcA); b = __shfl((int)pk1l, srcA); w0 = lo ? a : b;
        a = __shfl((int)pk0h, srcA); b = __shfl((int)pk1h, srcA); w1 = lo ? a : b;
        a = __shfl((int)pk0l, srcB); b = __shfl((int)pk1l, srcB); w2 = lo ? a : b;
        a = __shfl((int)pk0h, srcB); b = __shfl((int)pk1h, srcB); w3 = lo ? a : b;
        a = __shfl((int)pk2l, srcA); b = __shfl((int)pk3l, srcA); x0 = lo ? a : b;
        a = __shfl((int)pk2h, srcA); b = __shfl((int)pk3h, srcA); x1 = lo ? a : b;
        a = __shfl((int)pk2l, srcB); b = __shfl((int)pk3l, srcB); x2 = lo ? a : b;
        a = __shfl((int)pk2h, srcB); b = __shfl((int)pk3h, srcB); x3 = lo ? a : b;

        union { int4 i; bf16x8 v; } u0, u1;
        u0.i = make_int4(w0, w1, w2, w3);
        u1.i = make_int4(x0, x1, x2, x3);
        const bf16x8 pf0 = u0.v;   // keys 0..31 chunk (this lane: l4*8..+7)
        const bf16x8 pf1 = u1.v;   // keys 32..63 chunk

        // O += P V   (V^T tile: rows d, cols key)
        __builtin_amdgcn_s_setprio(1);
        #pragma unroll
        for (int db = 0; db < 4; ++db) {
            const int vrow = db * 16 + l15;
            const int sw = vrow & 7;
            bf16x8 vf0 = *reinterpret_cast<const bf16x8*>(VsB + vrow * 128 + ((l4 ^ sw) << 4));
            bf16x8 vf1 = *reinterpret_cast<const bf16x8*>(VsB + vrow * 128 + (((l4 + 4) ^ sw) << 4));
            accO[db] = __builtin_amdgcn_mfma_f32_16x16x32_bf16(pf0, vf0, accO[db], 0, 0, 0);
            accO[db] = __builtin_amdgcn_mfma_f32_16x16x32_bf16(pf1, vf1, accO[db], 0, 0, 0);
        }
        __builtin_amdgcn_s_setprio(0);
        __syncthreads();   // publishes prefetched tile, guards buffer reuse
    }

    // denom: lanes sharing q=l15 are {l15, l15^16, l15^32, l15^48}
    lsum += __shfl_xor(lsum, 16);
    lsum += __shfl_xor(lsum, 32);
    const float inv = 1.0f / lsum;

    float dr[4];
    #pragma unroll
    for (int r = 0; r < 4; ++r)
        dr[r] = __shfl(inv, l4 * 4 + r);   // denom for q-row l4*4+r (lane q holds it)

    const int n = nh >> 4, h = nh & 15;
    #pragma unroll
    for (int db = 0; db < 4; ++db) {
        const int d = h * 64 + db * 16 + l15;
        #pragma unroll
        for (int r = 0; r < 4; ++r) {
            const int s = q0 + waveQ + l4 * 4 + r;
            out[(size_t)n * S_LEN * EMB + (size_t)s * EMB + d] = accO[db][r] * dr[r];
        }
    }
}

extern "C" void kernel_launch(void* const* d_in, const int* in_sizes, int n_in,
                              void* d_out, int out_size, void* d_ws, size_t ws_size,
                              hipStream_t stream)
{
    const float* Xq = (const float*)d_in[0];
    const float* Xk = (const float*)d_in[1];
    const float* Xv = (const float*)d_in[2];
    const float* Wq = (const float*)d_in[3];
    const float* bq = (const float*)d_in[4];
    const float* Wk = (const float*)d_in[5];
    const float* bk = (const float*)d_in[6];
    const float* Wv = (const float*)d_in[7];
    const float* bv = (const float*)d_in[8];
    float* out = (float*)d_out;

    const size_t M4 = (size_t)4 * 1024 * 1024;   // u16 elements
    const size_t M1 = (size_t)1024 * 1024;

    u16* vt   = (u16*)d_ws;           // [64][64][1024]  V_att^T (q-proj)
    u16* katt = vt + M4;              // [64][1024][64]  K_att   (k-proj)
    u16* qatt = katt + M4;            // [64][1024][64]  Q_att   (v-proj)

    const size_t need = (3 * M4 + 3 * M4 + 3 * M1) * sizeof(u16);  // 54 MB

    if (ws_size >= need) {
        u16* Xqb = qatt + M4;
        u16* Xkb = Xqb + M4;
        u16* Xvb = Xkb + M4;
        u16* Wqb = Xvb + M4;
        u16* Wkb = Wqb + M1;
        u16* Wvb = Wkb + M1;

        CvtArgs ca;
        ca.src[0] = Xq; ca.src[1] = Xk; ca.src[2] = Xv;
        ca.src[3] = Wq; ca.src[4] = Wk; ca.src[5] = Wv;
        ca.dst[0] = Xqb; ca.dst[1] = Xkb; ca.dst[2] = Xvb;
        ca.dst[3] = Wqb; ca.dst[4] = Wkb; ca.dst[5] = Wvb;
        cvt_f32_bf16<<<2048, 256, 0, stream>>>(ca);

        qkv_gemm_bf16<<<dim3(32, 8, 3), 512, 0, stream>>>(
            Xqb, Xkb, Xvb, Wqb, Wkb, Wvb, bq, bk, bv, vt, katt, qatt);
    } else {
        qkv_gemm_f32<<<dim3(32, 8, 3), 256, 0, stream>>>(
            Xq, Xk, Xv, Wq, Wk, Wv, bq, bk, bv, vt, katt, qatt);
    }

    attn_kernel<<<dim3(16, 64), 256, 0, stream>>>(qatt, katt, vt, out);
}